// Round 1
// baseline (1604.098 us; speedup 1.0000x reference)
//
#include <hip/hip_runtime.h>

#define DEVFN __device__ __forceinline__

typedef __bf16 bf16x8 __attribute__((ext_vector_type(8)));
typedef float floatx4 __attribute__((ext_vector_type(4)));

// ---------- helpers ----------

DEVFN unsigned short f2bf(float x) {
    union { float f; unsigned u; } v; v.f = x;
    v.u += 0x7FFFu + ((v.u >> 16) & 1u);   // RNE
    return (unsigned short)(v.u >> 16);
}

DEVFN float sigm(float x) { return 1.f / (1.f + __expf(-x)); }
DEVFN float tanh_fast(float x) { float t = __expf(2.f * x); return 1.f - 2.f / (t + 1.f); }

DEVFN void gload_lds16(const unsigned short* g, unsigned short* l) {
    __builtin_amdgcn_global_load_lds(
        (__attribute__((address_space(1))) unsigned int*)g,
        (__attribute__((address_space(3))) unsigned int*)l, 16, 0, 0);
}

// ---------- conversion kernels ----------

// inputs [256,14,1024] f32 -> xt [14,256,1024] bf16
__global__ __launch_bounds__(256) void transpose_bt(const float* __restrict__ in,
                                                    unsigned short* __restrict__ out) {
    int idx = blockIdx.x * 256 + threadIdx.x;          // 0 .. 3584*1024-1
    int k = idx & 1023;
    int row = idx >> 10;                               // t*256 + b
    int t = row >> 8, b = row & 255;
    out[idx] = f2bf(in[(size_t)(b * 14 + t) * 1024 + k]);
}

__global__ __launch_bounds__(256) void f32_to_bf16(const float* __restrict__ in,
                                                   unsigned short* __restrict__ out,
                                                   int n_src, int n_total) {
    int idx = blockIdx.x * 256 + threadIdx.x;
    if (idx < n_total) out[idx] = (idx < n_src) ? f2bf(in[idx]) : (unsigned short)0;
}

__global__ __launch_bounds__(256) void bias_sum(const float* __restrict__ a,
                                                const float* __restrict__ b,
                                                float* __restrict__ o, int n) {
    int i = blockIdx.x * 256 + threadIdx.x;
    if (i < n) o[i] = a[i] + b[i];
}

// ---------- GEMM: out[m,n] = sum_k A[m,k]*W[n,k] (+bias[n]) (+pre[m,n]) ----------
// A,W bf16 row-major with row stride 1024 (all operands here have K-per-source 1024).
// Concat-K: k-tiles [0,k1t) from A1/W1, [k1t,k1t+k2t) from A2/W2.
// BM x BN tile, 256 threads = 4 waves in 2x2, mfma 16x16x32 bf16, m97 structure.
template <int BM, int BN>
__global__ __launch_bounds__(256)
void gemm_bt(const unsigned short* __restrict__ A1, const unsigned short* __restrict__ W1, int k1t,
             const unsigned short* __restrict__ A2, const unsigned short* __restrict__ W2, int k2t,
             const float* __restrict__ pre,
             const float* __restrict__ bias,
             float* __restrict__ out,
             int N, int Nreal, int remap) {
    constexpr int FM = BM / 32, FN = BN / 32;     // 16x16 frags per wave (2x2 wave grid)
    constexpr int AISS = (BM * 32 * 2) / 4096;    // staging issues (256 thr x 16B = 4KB)
    constexpr int BISS = (BN * 32 * 2) / 4096;

    __shared__ unsigned short ldsA[BM * 32];
    __shared__ unsigned short ldsB[BN * 32];

    const int tid = threadIdx.x;
    const int m0 = blockIdx.y * BM;
    const int n0 = blockIdx.x * BN;
    const int lane = tid & 63;
    const int wv = tid >> 6;
    const int wm = wv >> 1, wn = wv & 1;
    const int r16 = lane & 15;
    const int kg = lane >> 4;

    floatx4 acc[FM][FN];
#pragma unroll
    for (int i = 0; i < FM; ++i)
#pragma unroll
        for (int j = 0; j < FN; ++j) acc[i][j] = {0.f, 0.f, 0.f, 0.f};

    const int ktot = k1t + k2t;
    for (int kt = 0; kt < ktot; ++kt) {
        const unsigned short* As;
        const unsigned short* Ws;
        int ko;
        if (kt < k1t) { As = A1; Ws = W1; ko = kt * 32; }
        else          { As = A2; Ws = W2; ko = (kt - k1t) * 32; }
#pragma unroll
        for (int is = 0; is < AISS; ++is) {
            int c = is * 256 + tid;
            int row = c >> 2, kq = c & 3;
            gload_lds16(As + (size_t)(m0 + row) * 1024 + ko + kq * 8, &ldsA[c * 8]);
        }
#pragma unroll
        for (int is = 0; is < BISS; ++is) {
            int c = is * 256 + tid;
            int row = c >> 2, kq = c & 3;
            gload_lds16(Ws + (size_t)(n0 + row) * 1024 + ko + kq * 8, &ldsB[c * 8]);
        }
        __syncthreads();   // compiler emits vmcnt(0) before barrier -> loads landed

        bf16x8 a[FM], b[FN];
#pragma unroll
        for (int i = 0; i < FM; ++i)
            a[i] = *(const bf16x8*)&ldsA[(wm * (BM / 2) + i * 16 + r16) * 32 + kg * 8];
#pragma unroll
        for (int j = 0; j < FN; ++j)
            b[j] = *(const bf16x8*)&ldsB[(wn * (BN / 2) + j * 16 + r16) * 32 + kg * 8];
#pragma unroll
        for (int i = 0; i < FM; ++i)
#pragma unroll
            for (int j = 0; j < FN; ++j)
                acc[i][j] = __builtin_amdgcn_mfma_f32_16x16x32_bf16(a[i], b[j], acc[i][j], 0, 0, 0);
        __syncthreads();   // protect LDS before next stage
    }

    // epilogue: C/D frag layout col=lane&15, row=(lane>>4)*4+reg  [m89/m91]
#pragma unroll
    for (int i = 0; i < FM; ++i)
#pragma unroll
        for (int j = 0; j < FN; ++j)
#pragma unroll
            for (int rg = 0; rg < 4; ++rg) {
                int gm = m0 + wm * (BM / 2) + i * 16 + kg * 4 + rg;
                int gn = n0 + wn * (BN / 2) + j * 16 + r16;
                float v = acc[i][j][rg];
                if (bias != nullptr && gn < Nreal) v += bias[gn];
                if (pre != nullptr) v += pre[(size_t)gm * N + gn];
                if (!remap) {
                    out[(size_t)gm * N + gn] = v;
                } else if (gn < Nreal) {
                    int bb = gm & 255, tt = gm >> 8;   // row = t*256 + b
                    out[(size_t)(bb * 14 + tt) * Nreal + gn] = v;
                }
            }
}

// ---------- LSTM cell elementwise ----------
// g [M,4096] f32 (i|f|g|o), c_in [M,1024] f32 (nullptr => zeros),
// writes c_out f32 and h_out bf16. c_in may alias c_out.
__global__ __launch_bounds__(256)
void lstm_cell(const float* __restrict__ g, const float* c_in,
               float* c_out, unsigned short* __restrict__ h_out, int M) {
    int idx = blockIdx.x * 256 + threadIdx.x;
    if (idx >= (M << 8)) return;
    int m = idx >> 8, q = idx & 255;
    const float4* gp = (const float4*)(g + (size_t)m * 4096);
    float4 vi = gp[q];
    float4 vf = gp[q + 256];
    float4 vg = gp[q + 512];
    float4 vo = gp[q + 768];
    float4 cv = make_float4(0.f, 0.f, 0.f, 0.f);
    if (c_in) cv = *(const float4*)(c_in + (size_t)m * 1024 + q * 4);
    float ci[4] = {cv.x, cv.y, cv.z, cv.w};
    float gi[4] = {vi.x, vi.y, vi.z, vi.w};
    float gf[4] = {vf.x, vf.y, vf.z, vf.w};
    float gg[4] = {vg.x, vg.y, vg.z, vg.w};
    float go[4] = {vo.x, vo.y, vo.z, vo.w};
    float cn[4], hn[4];
#pragma unroll
    for (int j = 0; j < 4; ++j) {
        float iv = sigm(gi[j]);
        float fv = sigm(gf[j]);
        float gv = tanh_fast(gg[j]);
        float ov = sigm(go[j]);
        cn[j] = fv * ci[j] + iv * gv;
        hn[j] = ov * tanh_fast(cn[j]);
    }
    *(float4*)(c_out + (size_t)m * 1024 + q * 4) = make_float4(cn[0], cn[1], cn[2], cn[3]);
    uint2 hp;
    hp.x = (unsigned)f2bf(hn[0]) | ((unsigned)f2bf(hn[1]) << 16);
    hp.y = (unsigned)f2bf(hn[2]) | ((unsigned)f2bf(hn[3]) << 16);
    *(uint2*)(h_out + (size_t)m * 1024 + q * 4) = hp;
}

// ---------- launch ----------

extern "C" void kernel_launch(void* const* d_in, const int* in_sizes, int n_in,
                              void* d_out, int out_size, void* d_ws, size_t ws_size,
                              hipStream_t stream) {
    (void)in_sizes; (void)n_in; (void)out_size; (void)ws_size;
    const float* inputs   = (const float*)d_in[0];
    const float* roll_Wih = (const float*)d_in[1];
    const float* roll_Whh = (const float*)d_in[2];
    const float* roll_bih = (const float*)d_in[3];
    const float* roll_bhh = (const float*)d_in[4];
    const float* un_Wih   = (const float*)d_in[5];
    const float* un_Whh   = (const float*)d_in[6];
    const float* un_bih   = (const float*)d_in[7];
    const float* un_bhh   = (const float*)d_in[8];
    const float* cls_Wf   = (const float*)d_in[9];
    const float* cls_b    = (const float*)d_in[10];
    float* out = (float*)d_out;

    // workspace carve-up (~178 MB)
    char* ws = (char*)d_ws;
    size_t off = 0;
    auto alloc = [&](size_t bytes) -> char* {
        char* p = ws + off;
        off += (bytes + 255) & ~(size_t)255;
        return p;
    };
    unsigned short* xt   = (unsigned short*)alloc(3584ull * 1024 * 2);  // [t*256+b][1024]
    unsigned short* rWih = (unsigned short*)alloc(4096ull * 1024 * 2);
    unsigned short* rWhh = (unsigned short*)alloc(4096ull * 1024 * 2);
    unsigned short* uWih = (unsigned short*)alloc(4096ull * 1024 * 2);
    unsigned short* uWhh = (unsigned short*)alloc(4096ull * 1024 * 2);
    unsigned short* cWp  = (unsigned short*)alloc(2560ull * 1024 * 2);  // cls_W padded to 2560 rows
    float* rbias = (float*)alloc(4096 * 4);
    float* ubias = (float*)alloc(4096 * 4);
    float* Xpre  = (float*)alloc(3584ull * 4096 * 4);  // unroll x-projection (+bias)
    float* gbuf  = (float*)alloc(3584ull * 4096 * 4);  // gate preactivation scratch
    float* uc    = (float*)alloc(3584ull * 1024 * 4);  // unroll cell state  [t*256+b]
    unsigned short* uh = (unsigned short*)alloc(3584ull * 1024 * 2);  // unroll h (bf16)

    const size_t SF = 256 * 1024;  // per-t row block (elements)

    // 1) conversions
    transpose_bt<<<14336, 256, 0, stream>>>(inputs, xt);
    f32_to_bf16<<<16384, 256, 0, stream>>>(roll_Wih, rWih, 4194304, 4194304);
    f32_to_bf16<<<16384, 256, 0, stream>>>(roll_Whh, rWhh, 4194304, 4194304);
    f32_to_bf16<<<16384, 256, 0, stream>>>(un_Wih, uWih, 4194304, 4194304);
    f32_to_bf16<<<16384, 256, 0, stream>>>(un_Whh, uWhh, 4194304, 4194304);
    f32_to_bf16<<<10240, 256, 0, stream>>>(cls_Wf, cWp, 2573312, 2621440);
    bias_sum<<<16, 256, 0, stream>>>(roll_bih, roll_bhh, rbias, 4096);
    bias_sum<<<16, 256, 0, stream>>>(un_bih, un_bhh, ubias, 4096);

    // 2) unroll input projection: Xpre = xt @ uWih^T + ubias   [3584,4096]
    gemm_bt<128, 128><<<dim3(32, 28), 256, 0, stream>>>(
        xt, uWih, 32, xt, uWih, 0, nullptr, ubias, Xpre, 4096, 4096, 0);

    // 3) rolling LSTM: 14 steps, state written into branch-major unroll buffers
    for (int t = 0; t < 14; ++t) {
        const unsigned short* hprev = (t == 0) ? xt /*unused*/ : uh + (size_t)(t - 1) * SF;
        int k2t = (t == 0) ? 0 : 32;
        gemm_bt<64, 64><<<dim3(64, 4), 256, 0, stream>>>(
            xt + (size_t)t * SF, rWih, 32, hprev, rWhh, k2t,
            nullptr, rbias, gbuf, 4096, 4096, 0);
        const float* cprev = (t == 0) ? nullptr : uc + (size_t)(t - 1) * SF;
        lstm_cell<<<256, 256, 0, stream>>>(gbuf, cprev, uc + (size_t)t * SF,
                                           uh + (size_t)t * SF, 256);
    }

    // 4) unrolling LSTM: 15 steps over shrinking contiguous branch prefix
    for (int s = 0; s <= 14; ++s) {
        int nb = (15 - s < 14) ? (15 - s) : 14;
        int M = nb * 256;
        if (M >= 1024) {
            gemm_bt<128, 128><<<dim3(32, M / 128), 256, 0, stream>>>(
                uh, uWhh, 32, uh, uWhh, 0, Xpre, nullptr, gbuf, 4096, 4096, 0);
        } else {
            gemm_bt<64, 64><<<dim3(64, M / 64), 256, 0, stream>>>(
                uh, uWhh, 32, uh, uWhh, 0, Xpre, nullptr, gbuf, 4096, 4096, 0);
        }
        lstm_cell<<<M, 256, 0, stream>>>(gbuf, uc, uc, uh, M);
    }
    // uh now holds h_n (bf16) for every (t,b)

    // 5) classifier: out[b,t,:] = uh[t*256+b,:] @ cls_W^T + cls_b
    gemm_bt<128, 128><<<dim3(20, 28), 256, 0, stream>>>(
        uh, cWp, 32, uh, cWp, 0, nullptr, cls_b, out, 2560, 2513, 1);
}

// Round 2
// 1126.236 us; speedup vs baseline: 1.4243x; 1.4243x over previous
//
#include <hip/hip_runtime.h>

#define DEVFN __device__ __forceinline__

typedef __bf16 bf16x8 __attribute__((ext_vector_type(8)));
typedef float floatx4 __attribute__((ext_vector_type(4)));

// ---------- helpers ----------

DEVFN unsigned short f2bf(float x) {
    union { float f; unsigned u; } v; v.f = x;
    v.u += 0x7FFFu + ((v.u >> 16) & 1u);   // RNE
    return (unsigned short)(v.u >> 16);
}

DEVFN float sigm(float x) { return 1.f / (1.f + __expf(-x)); }
DEVFN float tanh_fast(float x) { float t = __expf(2.f * x); return 1.f - 2.f / (t + 1.f); }

DEVFN void gload_lds16(const unsigned short* g, unsigned short* l) {
    __builtin_amdgcn_global_load_lds(
        (__attribute__((address_space(1))) unsigned int*)g,
        (__attribute__((address_space(3))) unsigned int*)l, 16, 0, 0);
}

// ---------- conversion kernels ----------

// inputs [256,14,1024] f32 -> xt [14,256,1024] bf16
__global__ __launch_bounds__(256) void transpose_bt(const float* __restrict__ in,
                                                    unsigned short* __restrict__ out) {
    int idx = blockIdx.x * 256 + threadIdx.x;
    int k = idx & 1023;
    int row = idx >> 10;                               // t*256 + b
    int t = row >> 8, b = row & 255;
    out[idx] = f2bf(in[(size_t)(b * 14 + t) * 1024 + k]);
}

__global__ __launch_bounds__(256) void f32_to_bf16(const float* __restrict__ in,
                                                   unsigned short* __restrict__ out,
                                                   int n_src, int n_total) {
    int idx = blockIdx.x * 256 + threadIdx.x;
    if (idx < n_total) out[idx] = (idx < n_src) ? f2bf(in[idx]) : (unsigned short)0;
}

// bias (gate-major [4][1024]) -> gate-interleaved float4 [1024][4]
__global__ __launch_bounds__(256) void bias_interleave(const float* __restrict__ a,
                                                       const float* __restrict__ b,
                                                       float* __restrict__ o4, int n) {
    int i = blockIdx.x * 256 + threadIdx.x;
    if (i < n) {
        int g = i >> 10, h = i & 1023;
        o4[h * 4 + g] = a[i] + b[i];
    }
}

// ---------- fused LSTM GEMM ----------
// MODE 0: gates store  -> gout[(m*1024+h)*4 + {i,f,g,o}] = acc + bias4
// MODE 1: LSTM cell    -> c_out, h_out (bf16), pre4/bias4 added to gates
// MODE 2: classifier   -> outp[(b*14+t)*2513 + n] = acc + clsb[n]   (m = t*256+b)
//
// B-tile (MODE 0/1): 128 LDS rows = 4 gates x 32 h-cols gathered so that a
// thread's j-fragments are the 4 gates at one (m,h).  col c=r: gate=(c>>4)&3,
// h = n0 + (c>>6)*16 + (c&15).  MODE 2: plain rows n0+r.
// LDS k-chunks XOR-swizzled via pre-swizzled GLOBAL source (rule 21):
// LDS(row,kq) holds global chunk kq^(row&7); reads apply the same XOR.
template <int BM, int MODE>
__global__ __launch_bounds__(256)
void lstm_fused(const unsigned short* __restrict__ A1, const unsigned short* __restrict__ W1, int k1t,
                const unsigned short* __restrict__ A2, const unsigned short* __restrict__ W2, int k2t,
                const float* __restrict__ pre4,
                const float* __restrict__ bias4,
                const float* __restrict__ c_in,
                float* __restrict__ c_out,
                unsigned short* __restrict__ h_out,
                unsigned short* __restrict__ h_alt, int retire_t,
                float* __restrict__ gout,
                const float* __restrict__ clsb,
                float* __restrict__ outp) {
    constexpr int BK = 64;
    constexpr int FM = BM / 32;                 // m-frags per wave (2x2 wave grid)
    constexpr int AISS = (BM * BK * 2) / 4096;  // staging issues (256 thr x 16B)
    constexpr int BISS = (128 * BK * 2) / 4096;

    __shared__ unsigned short ldsA[BM * BK];
    __shared__ unsigned short ldsB[128 * BK];

    const int tid = threadIdx.x;
    const int m0 = blockIdx.y * BM;
    const int n0 = blockIdx.x * ((MODE == 2) ? 128 : 32);
    const int lane = tid & 63;
    const int wv = tid >> 6;
    const int wm = wv >> 1, wn = wv & 1;
    const int r16 = lane & 15;
    const int kg = lane >> 4;

    floatx4 acc[FM][4];
#pragma unroll
    for (int i = 0; i < FM; ++i)
#pragma unroll
        for (int j = 0; j < 4; ++j) acc[i][j] = {0.f, 0.f, 0.f, 0.f};

    const int ktot = k1t + k2t;
    for (int kt = 0; kt < ktot; ++kt) {
        const unsigned short* As;
        const unsigned short* Ws;
        int ko;
        if (kt < k1t) { As = A1; Ws = W1; ko = kt * BK; }
        else          { As = A2; Ws = W2; ko = (kt - k1t) * BK; }
#pragma unroll
        for (int is = 0; is < AISS; ++is) {
            int c = is * 256 + tid;
            int row = c >> 3, kq = c & 7;
            int kqg = kq ^ (row & 7);           // pre-swizzled source chunk
            gload_lds16(As + (size_t)(m0 + row) * 1024 + ko + kqg * 8, &ldsA[c * 8]);
        }
#pragma unroll
        for (int is = 0; is < BISS; ++is) {
            int c = is * 256 + tid;
            int row = c >> 3, kq = c & 7;
            int kqg = kq ^ (row & 7);
            int wr;
            if (MODE == 2) wr = n0 + row;
            else wr = ((row >> 4) & 3) * 1024 + n0 + ((row >> 6) << 4) + (row & 15);
            gload_lds16(Ws + (size_t)wr * 1024 + ko + kqg * 8, &ldsB[c * 8]);
        }
        __syncthreads();

#pragma unroll
        for (int kk = 0; kk < 2; ++kk) {
            bf16x8 a[FM], b[4];
            const int kqg = kk * 4 + kg;
#pragma unroll
            for (int i = 0; i < FM; ++i) {
                int row = wm * (BM / 2) + i * 16 + r16;
                a[i] = *(const bf16x8*)&ldsA[row * BK + (kqg ^ (row & 7)) * 8];
            }
#pragma unroll
            for (int j = 0; j < 4; ++j) {
                int row = wn * 64 + j * 16 + r16;
                b[j] = *(const bf16x8*)&ldsB[row * BK + (kqg ^ (row & 7)) * 8];
            }
#pragma unroll
            for (int i = 0; i < FM; ++i)
#pragma unroll
                for (int j = 0; j < 4; ++j)
                    acc[i][j] = __builtin_amdgcn_mfma_f32_16x16x32_bf16(a[i], b[j], acc[i][j], 0, 0, 0);
        }
        __syncthreads();
    }

    // ---------- epilogue ----------
    if (MODE == 2) {
#pragma unroll
        for (int i = 0; i < FM; ++i)
#pragma unroll
            for (int j = 0; j < 4; ++j)
#pragma unroll
                for (int rg = 0; rg < 4; ++rg) {
                    int m = m0 + wm * (BM / 2) + i * 16 + kg * 4 + rg;
                    int gn = n0 + wn * 64 + j * 16 + r16;
                    if (gn < 2513) {
                        int bb = m & 255, tt = m >> 8;
                        outp[(size_t)(bb * 14 + tt) * 2513 + gn] = acc[i][j][rg] + clsb[gn];
                    }
                }
        return;
    }

    const int h = n0 + wn * 16 + r16;
    float4 bv = make_float4(0.f, 0.f, 0.f, 0.f);
    if (bias4) bv = *(const float4*)(bias4 + (size_t)h * 4);
    const float4* pre = (const float4*)pre4;
    unsigned short* hw = h_out;
    if (MODE == 1 && (m0 >> 8) == retire_t) hw = h_alt;

#pragma unroll
    for (int i = 0; i < FM; ++i)
#pragma unroll
        for (int rg = 0; rg < 4; ++rg) {
            int m = m0 + wm * (BM / 2) + i * 16 + kg * 4 + rg;
            size_t mh = (size_t)m * 1024 + h;
            float gi_ = acc[i][0][rg] + bv.x;
            float gf_ = acc[i][1][rg] + bv.y;
            float gg_ = acc[i][2][rg] + bv.z;
            float go_ = acc[i][3][rg] + bv.w;
            if (MODE == 0) {
                *(float4*)(gout + mh * 4) = make_float4(gi_, gf_, gg_, go_);
            } else {
                if (pre) {
                    float4 pv = pre[mh];
                    gi_ += pv.x; gf_ += pv.y; gg_ += pv.z; go_ += pv.w;
                }
                float co = c_in ? c_in[mh] : 0.f;
                float iv = sigm(gi_), fv = sigm(gf_);
                float gv = tanh_fast(gg_), ov = sigm(go_);
                float cn = fv * co + iv * gv;
                float hn = ov * tanh_fast(cn);
                c_out[mh] = cn;
                hw[mh] = f2bf(hn);
            }
        }
}

// ---------- launch ----------

extern "C" void kernel_launch(void* const* d_in, const int* in_sizes, int n_in,
                              void* d_out, int out_size, void* d_ws, size_t ws_size,
                              hipStream_t stream) {
    (void)in_sizes; (void)n_in; (void)out_size; (void)ws_size;
    const float* inputs   = (const float*)d_in[0];
    const float* roll_Wih = (const float*)d_in[1];
    const float* roll_Whh = (const float*)d_in[2];
    const float* roll_bih = (const float*)d_in[3];
    const float* roll_bhh = (const float*)d_in[4];
    const float* un_Wih   = (const float*)d_in[5];
    const float* un_Whh   = (const float*)d_in[6];
    const float* un_bih   = (const float*)d_in[7];
    const float* un_bhh   = (const float*)d_in[8];
    const float* cls_Wf   = (const float*)d_in[9];
    const float* cls_b    = (const float*)d_in[10];
    float* out = (float*)d_out;

    char* ws = (char*)d_ws;
    size_t off = 0;
    auto alloc = [&](size_t bytes) -> char* {
        char* p = ws + off;
        off += (bytes + 255) & ~(size_t)255;
        return p;
    };
    unsigned short* xt   = (unsigned short*)alloc(3584ull * 1024 * 2);
    unsigned short* rWih = (unsigned short*)alloc(4096ull * 1024 * 2);
    unsigned short* rWhh = (unsigned short*)alloc(4096ull * 1024 * 2);
    unsigned short* uWih = (unsigned short*)alloc(4096ull * 1024 * 2);
    unsigned short* uWhh = (unsigned short*)alloc(4096ull * 1024 * 2);
    unsigned short* cWp  = (unsigned short*)alloc(2560ull * 1024 * 2);
    float* rbias4 = (float*)alloc(1024 * 4 * 4);
    float* ubias4 = (float*)alloc(1024 * 4 * 4);
    float* Xpre   = (float*)alloc(3584ull * 4096 * 4);   // gate-interleaved [m][h][4]
    float* uc     = (float*)alloc(3584ull * 1024 * 4);
    unsigned short* hb0    = (unsigned short*)alloc(3584ull * 1024 * 2);
    unsigned short* hb1    = (unsigned short*)alloc(3584ull * 1024 * 2);
    unsigned short* hfinal = (unsigned short*)alloc(3584ull * 1024 * 2);

    const size_t SF = 256 * 1024;

    // 1) conversions
    transpose_bt<<<14336, 256, 0, stream>>>(inputs, xt);
    f32_to_bf16<<<16384, 256, 0, stream>>>(roll_Wih, rWih, 4194304, 4194304);
    f32_to_bf16<<<16384, 256, 0, stream>>>(roll_Whh, rWhh, 4194304, 4194304);
    f32_to_bf16<<<16384, 256, 0, stream>>>(un_Wih, uWih, 4194304, 4194304);
    f32_to_bf16<<<16384, 256, 0, stream>>>(un_Whh, uWhh, 4194304, 4194304);
    f32_to_bf16<<<10240, 256, 0, stream>>>(cls_Wf, cWp, 2573312, 2621440);
    bias_interleave<<<16, 256, 0, stream>>>(roll_bih, roll_bhh, rbias4, 4096);
    bias_interleave<<<16, 256, 0, stream>>>(un_bih, un_bhh, ubias4, 4096);

    // 2) unroll input projection -> Xpre (gate-interleaved, +bias)
    lstm_fused<128, 0><<<dim3(32, 28), 256, 0, stream>>>(
        xt, uWih, 16, nullptr, nullptr, 0,
        nullptr, ubias4, nullptr, nullptr, nullptr, nullptr, -1,
        Xpre, nullptr, nullptr);

    // 3) rolling LSTM, fully fused (state lands branch-major in hb0/uc)
    for (int t = 0; t < 14; ++t) {
        const unsigned short* hprev = (t == 0) ? xt : hb0 + (size_t)(t - 1) * SF;
        const float* cprev = (t == 0) ? nullptr : uc + (size_t)(t - 1) * SF;
        lstm_fused<64, 1><<<dim3(32, 4), 256, 0, stream>>>(
            xt + (size_t)t * SF, rWih, 16, hprev, rWhh, (t == 0) ? 0 : 16,
            nullptr, rbias4, cprev, uc + (size_t)t * SF,
            hb0 + (size_t)t * SF, nullptr, -1, nullptr, nullptr, nullptr);
    }

    // 4) unrolling LSTM, fused; h ping-pongs, retiring branch writes hfinal
    for (int s = 0; s <= 14; ++s) {
        int nb = (15 - s < 14) ? (15 - s) : 14;
        int M = nb * 256;
        const unsigned short* hsrc = (s & 1) ? hb1 : hb0;
        unsigned short* hdst = (s & 1) ? hb0 : hb1;
        lstm_fused<128, 1><<<dim3(32, M / 128), 256, 0, stream>>>(
            hsrc, uWhh, 16, nullptr, nullptr, 0,
            Xpre, nullptr, uc, uc, hdst, hfinal, (s >= 1) ? (14 - s) : -1,
            nullptr, nullptr, nullptr);
    }

    // 5) classifier from hfinal
    lstm_fused<128, 2><<<dim3(20, 28), 256, 0, stream>>>(
        hfinal, cWp, 16, nullptr, nullptr, 0,
        nullptr, nullptr, nullptr, nullptr, nullptr, nullptr, -1,
        nullptr, cls_b, out);
}